// Round 1
// baseline (9.703 us; speedup 1.0000x reference)
//
#include <hip/hip_runtime.h>

// The reference's final op is softmax over a singleton axis (axis=1 of a
// (B,1,W) tensor), which is identically 1.0 for any finite input. The entire
// upstream graph (BiConvLSTMs, attention, dense) is mathematically dead.
// Output = ones((16,1,32), float32) = 512 floats of 1.0f.

__global__ void write_ones_kernel(float* __restrict__ out, int n) {
    int i = blockIdx.x * blockDim.x + threadIdx.x;
    if (i < n) out[i] = 1.0f;
}

extern "C" void kernel_launch(void* const* d_in, const int* in_sizes, int n_in,
                              void* d_out, int out_size, void* d_ws, size_t ws_size,
                              hipStream_t stream) {
    float* out = (float*)d_out;
    const int threads = 256;
    const int blocks = (out_size + threads - 1) / threads;
    write_ones_kernel<<<blocks, threads, 0, stream>>>(out, out_size);
}